// Round 2
// baseline (1122.303 us; speedup 1.0000x reference)
//
#include <hip/hip_runtime.h>

#define BB 32
#define NN 512
#define FF 128
#define K4 2048
#define ALPHA 0.2f
#define THRESH 0.6f
#define NEGINF -9e15f

typedef unsigned short u16;
typedef __attribute__((ext_vector_type(8))) short short8;
typedef __attribute__((ext_vector_type(4))) float f32x4;

__device__ __forceinline__ u16 f2bf(float x) {
    unsigned b = __float_as_uint(x);
    b += 0x7fffu + ((b >> 16) & 1u);
    return (u16)(b >> 16);
}
__device__ __forceinline__ float bf2f(u16 u) { return __uint_as_float(((unsigned)u) << 16); }
__device__ __forceinline__ float lrelu(float x) { return x > 0.f ? x : ALPHA * x; }

__device__ __forceinline__ void gload16(const void* g, void* l) {
    __builtin_amdgcn_global_load_lds(
        (__attribute__((address_space(1))) const unsigned int*)(unsigned long long)g,
        (__attribute__((address_space(3))) unsigned int*)(unsigned int)(unsigned long long)l,
        16, 0, 0);
}

// u1[f] = sum_g W[g,f]*a[g];  u2[f] = sum_g W[g,f]*a[F+g]
__global__ void k_u(const float* __restrict__ W, const float* __restrict__ a,
                    float* __restrict__ u12) {
    int f = threadIdx.x;
    float s1 = 0.f, s2 = 0.f;
    for (int g = 0; g < FF; ++g) {
        float w = W[g * FF + f];
        s1 += w * a[g];
        s2 += w * a[FF + g];
    }
    u12[f] = s1;
    u12[FF + f] = s2;
}

// Wh1[row] = h[row,:]·u1 ; Wh2[row] = h[row,:]·u2
__global__ void k_wh12(const float* __restrict__ h, const float* __restrict__ u12,
                       float* __restrict__ Wh12) {
    int row = blockIdx.x;
    int f = threadIdx.x;  // 128
    float hv = h[(size_t)row * FF + f];
    float p1 = hv * u12[f], p2 = hv * u12[FF + f];
#pragma unroll
    for (int o = 1; o < 64; o <<= 1) {
        p1 += __shfl_xor(p1, o, 64);
        p2 += __shfl_xor(p2, o, 64);
    }
    __shared__ float s1[2], s2[2];
    int w = f >> 6;
    if ((f & 63) == 0) { s1[w] = p1; s2[w] = p2; }
    __syncthreads();
    if (f == 0) {
        Wh12[row] = s1[0] + s1[1];
        Wh12[BB * NN + row] = s2[0] + s2[1];
    }
}

// WhT[b][f][n] = (h@W^T)[b][n][f] split into bf16 hi/lo.  C[f,mg] = sum_k W[f,k] h[mg,k]
__global__ __launch_bounds__(256) void k_whT(const float* __restrict__ W,
                                             const float* __restrict__ h,
                                             u16* __restrict__ Thi, u16* __restrict__ Tlo) {
    const int bm = blockIdx.y * 64, bn = blockIdx.x * 64;
    __shared__ float As[32][68];
    __shared__ float Bs[32][68];
    int tid = threadIdx.x;
    int tx = tid & 15, ty = tid >> 4;
    float acc[4][4] = {{0.f}};
    int r = tid >> 3, q = tid & 7;
    const float* Ap = W + (size_t)(bm + r) * FF + q * 4;
    const float* Bp = h + (size_t)(bn + r) * FF + q * 4;
    for (int k0 = 0; k0 < FF; k0 += 32) {
        float4 a0 = *(const float4*)(Ap + k0);
        float4 a1 = *(const float4*)(Ap + k0 + 32 * FF);
        float4 b0 = *(const float4*)(Bp + k0);
        float4 b1 = *(const float4*)(Bp + k0 + 32 * FF);
        __syncthreads();
        As[q * 4 + 0][r] = a0.x; As[q * 4 + 1][r] = a0.y;
        As[q * 4 + 2][r] = a0.z; As[q * 4 + 3][r] = a0.w;
        As[q * 4 + 0][r + 32] = a1.x; As[q * 4 + 1][r + 32] = a1.y;
        As[q * 4 + 2][r + 32] = a1.z; As[q * 4 + 3][r + 32] = a1.w;
        Bs[q * 4 + 0][r] = b0.x; Bs[q * 4 + 1][r] = b0.y;
        Bs[q * 4 + 2][r] = b0.z; Bs[q * 4 + 3][r] = b0.w;
        Bs[q * 4 + 0][r + 32] = b1.x; Bs[q * 4 + 1][r + 32] = b1.y;
        Bs[q * 4 + 2][r + 32] = b1.z; Bs[q * 4 + 3][r + 32] = b1.w;
        __syncthreads();
#pragma unroll
        for (int kk = 0; kk < 32; ++kk) {
            float av[4], bv[4];
            *(float4*)av = *(const float4*)&As[kk][ty * 4];
            *(float4*)bv = *(const float4*)&Bs[kk][tx * 4];
#pragma unroll
            for (int i = 0; i < 4; ++i)
#pragma unroll
                for (int j = 0; j < 4; ++j) acc[i][j] = fmaf(av[i], bv[j], acc[i][j]);
        }
    }
#pragma unroll
    for (int i = 0; i < 4; ++i) {
        int f = bm + ty * 4 + i;
#pragma unroll
        for (int j = 0; j < 4; ++j) {
            int mg = bn + tx * 4 + j;
            float v = acc[i][j];
            u16 hi = f2bf(v);
            u16 lo = f2bf(v - bf2f(hi));
            size_t idx = ((size_t)(mg >> 9) * FF + f) * NN + (mg & 511);
            Thi[idx] = hi;
            Tlo[idx] = lo;
        }
    }
}

// fp32 -> bf16 hi/lo split, vectorized
__global__ void k_split(const float* __restrict__ X, u16* __restrict__ Hi,
                        u16* __restrict__ Lo, int n4) {
    int i = blockIdx.x * 256 + threadIdx.x;
    if (i >= n4) return;
    float4 v = *(const float4*)(X + (size_t)i * 4);
    u16 h0 = f2bf(v.x), h1 = f2bf(v.y), h2 = f2bf(v.z), h3 = f2bf(v.w);
    ushort4 hh = make_ushort4(h0, h1, h2, h3);
    ushort4 ll = make_ushort4(f2bf(v.x - bf2f(h0)), f2bf(v.y - bf2f(h1)),
                              f2bf(v.z - bf2f(h2)), f2bf(v.w - bf2f(h3)));
    *(ushort4*)(Hi + (size_t)i * 4) = hh;
    *(ushort4*)(Lo + (size_t)i * 4) = ll;
}

// E chunk: e[b,i,j] = lrelu(Wh1[b,i] + Wh2[b,j]) -> bf16 hi/lo
__global__ void k_e2(const float* __restrict__ Wh12, int c0, u16* __restrict__ Ehi,
                     u16* __restrict__ Elo) {
    const int i = blockIdx.x;
    const int bl = blockIdx.y;
    const int b = c0 + bl;
    const int t = threadIdx.x;  // 128
    const float w1 = Wh12[b * NN + i];
    const float* w2 = Wh12 + BB * NN + b * NN;
    const int j = t * 4;
    float4 v = *(const float4*)(w2 + j);
    float e0 = lrelu(w1 + v.x), e1 = lrelu(w1 + v.y);
    float e2 = lrelu(w1 + v.z), e3 = lrelu(w1 + v.w);
    u16 h0 = f2bf(e0), h1 = f2bf(e1), h2 = f2bf(e2), h3 = f2bf(e3);
    ushort4 hh = make_ushort4(h0, h1, h2, h3);
    ushort4 ll = make_ushort4(f2bf(e0 - bf2f(h0)), f2bf(e1 - bf2f(h1)),
                              f2bf(e2 - bf2f(h2)), f2bf(e3 - bf2f(h3)));
    const size_t idx = ((size_t)bl * NN + i) * NN + j;
    *(ushort4*)(Ehi + idx) = hh;
    *(ushort4*)(Elo + idx) = ll;
}

// Split-bf16 MFMA GEMM: C[m,n] = epi( sum_k A[m,k]*B[n,k] ), K' = 3K terms
// term0: Ahi*Bhi, term1: Alo*Bhi, term2: Ahi*Blo.  lda = ldb = K.
// 128x128 tile, 4 waves (2x2), fragment-linear LDS via global_load_lds.
// EPI 0: sigmoid -> Chi/Clo.  EPI 1: adj-mask -> ADJ (reads Eh/El).  EPI 2: elu -> OUT.
template <int EPI, int K>
__global__ __launch_bounds__(256) void k_mfma(
    const u16* __restrict__ Ahi, const u16* __restrict__ Alo, long sA,
    const u16* __restrict__ Bhi, const u16* __restrict__ Blo, long sB,
    u16* __restrict__ Chi, u16* __restrict__ Clo, long sC, int ldc,
    const u16* __restrict__ Eh, const u16* __restrict__ El, float* __restrict__ ADJ,
    float* __restrict__ OUT) {
    __shared__ __align__(16) u16 ldsA[4096];
    __shared__ __align__(16) u16 ldsB[4096];
    const int tid = threadIdx.x;
    const int l = tid & 63, w = tid >> 6;
    const int wr = w >> 1, wc = w & 1;
    const int bz = blockIdx.z;
    const int bm = blockIdx.y * 128, bn = blockIdx.x * 128;

    const u16* A0p = Ahi + (size_t)bz * sA;
    const u16* A1p = Alo + (size_t)bz * sA;
    const u16* B0p = Bhi + (size_t)bz * sB;
    const u16* B1p = Blo + (size_t)bz * sB;

    // staging: round r covers row-groups g = r*4 + w; lane -> row (l&15), k-chunk (l>>4)*8
    const size_t rA0 = (size_t)(bm + w * 16 + (l & 15)) * K;
    const size_t rA1 = (size_t)(bm + (4 + w) * 16 + (l & 15)) * K;
    const size_t rB0 = (size_t)(bn + w * 16 + (l & 15)) * K;
    const size_t rB1 = (size_t)(bn + (4 + w) * 16 + (l & 15)) * K;
    const int koff = (l >> 4) * 8;

    u16* dA0 = ldsA + (w * 64) * 8;
    u16* dA1 = ldsA + (256 + w * 64) * 8;
    u16* dB0 = ldsB + (w * 64) * 8;
    u16* dB1 = ldsB + (256 + w * 64) * 8;

    f32x4 acc[4][4];
#pragma unroll
    for (int m = 0; m < 4; ++m)
#pragma unroll
        for (int n = 0; n < 4; ++n) acc[m][n] = (f32x4){0.f, 0.f, 0.f, 0.f};

    constexpr int SPT = K / 32;
    int term = 0, tc = 0, kk = 0;
    for (int kt = 0; kt < 3 * SPT; ++kt) {
        const u16* Ap = (term == 1) ? A1p : A0p;
        const u16* Bp = (term == 2) ? B1p : B0p;
        const int col = kk + koff;
        gload16(Ap + rA0 + col, dA0);
        gload16(Ap + rA1 + col, dA1);
        gload16(Bp + rB0 + col, dB0);
        gload16(Bp + rB1 + col, dB1);
        __syncthreads();  // drains vmcnt -> LDS tiles ready
        short8 af[4], bf[4];
#pragma unroll
        for (int m = 0; m < 4; ++m) af[m] = *(const short8*)&ldsA[((wr * 4 + m) * 64 + l) * 8];
#pragma unroll
        for (int n = 0; n < 4; ++n) bf[n] = *(const short8*)&ldsB[((wc * 4 + n) * 64 + l) * 8];
#pragma unroll
        for (int m = 0; m < 4; ++m)
#pragma unroll
            for (int n = 0; n < 4; ++n)
                acc[m][n] =
                    __builtin_amdgcn_mfma_f32_16x16x32_bf16(af[m], bf[n], acc[m][n], 0, 0, 0);
        __syncthreads();  // protect LDS before next stage
        kk += 32;
        if (++tc == SPT) { tc = 0; kk = 0; ++term; }
    }

    const int lr = (l >> 4) * 4, lc = l & 15;
#pragma unroll
    for (int m = 0; m < 4; ++m) {
#pragma unroll
        for (int n = 0; n < 4; ++n) {
#pragma unroll
            for (int j = 0; j < 4; ++j) {
                const int row = bm + wr * 64 + m * 16 + lr + j;
                const int col = bn + wc * 64 + n * 16 + lc;
                const float v = acc[m][n][j];
                if constexpr (EPI == 0) {
                    const float s = __fdividef(1.f, 1.f + __expf(-v));
                    const u16 hi = f2bf(s);
                    const u16 lo = f2bf(s - bf2f(hi));
                    const size_t idx = (size_t)bz * sC + (size_t)row * ldc + col;
                    Chi[idx] = hi;
                    Clo[idx] = lo;
                } else if constexpr (EPI == 1) {
                    const size_t idx = (size_t)bz * sC + (size_t)row * ldc + col;
                    const float e = bf2f(Eh[idx]) + bf2f(El[idx]);
                    ADJ[idx] = (e + v > THRESH) ? e : NEGINF;
                } else {
                    const size_t idx = (size_t)bz * (size_t)(NN * FF) + (size_t)row * FF + col;
                    OUT[idx] = v > 0.f ? v : __expf(v) - 1.f;
                }
            }
        }
    }
}

// softmax rows of ADJ (fp32), write att as bf16 hi/lo (into freed E buffers)
__global__ __launch_bounds__(256) void k_softmax2(const float* __restrict__ ADJ,
                                                  u16* __restrict__ Hi, u16* __restrict__ Lo) {
    const size_t row = blockIdx.x;
    const float* p = ADJ + row * NN;
    const int t = threadIdx.x;
    float v0 = p[t], v1 = p[t + 256];
    float m = fmaxf(v0, v1);
#pragma unroll
    for (int o = 1; o < 64; o <<= 1) m = fmaxf(m, __shfl_xor(m, o, 64));
    __shared__ float red[4], red2[4];
    int w = t >> 6;
    if ((t & 63) == 0) red[w] = m;
    __syncthreads();
    m = fmaxf(fmaxf(red[0], red[1]), fmaxf(red[2], red[3]));
    float e0 = __expf(v0 - m), e1 = __expf(v1 - m);
    float s = e0 + e1;
#pragma unroll
    for (int o = 1; o < 64; o <<= 1) s += __shfl_xor(s, o, 64);
    if ((t & 63) == 0) red2[w] = s;
    __syncthreads();
    s = red2[0] + red2[1] + red2[2] + red2[3];
    float inv = 1.f / s;
    float a0 = e0 * inv, a1 = e1 * inv;
    u16 h0 = f2bf(a0), h1 = f2bf(a1);
    Hi[row * NN + t] = h0;
    Hi[row * NN + t + 256] = h1;
    Lo[row * NN + t] = f2bf(a0 - bf2f(h0));
    Lo[row * NN + t + 256] = f2bf(a1 - bf2f(h1));
}

extern "C" void kernel_launch(void* const* d_in, const int* in_sizes, int n_in,
                              void* d_out, int out_size, void* d_ws, size_t ws_size,
                              hipStream_t stream) {
    const float* h = (const float*)d_in[0];
    const float* W = (const float*)d_in[1];
    const float* a = (const float*)d_in[2];
    const float* A0 = (const float*)d_in[3];
    const float* A2 = (const float*)d_in[4];
    float* out = (float*)d_out;

    char* ws = (char*)d_ws;
    size_t ofs = 0;
    auto alloc = [&](size_t bytes) -> void* {
        void* p = ws + ofs;
        ofs = (ofs + bytes + 255) & ~(size_t)255;
        return p;
    };
    float* u12 = (float*)alloc(2 * FF * sizeof(float));
    float* Wh12 = (float*)alloc(2 * (size_t)BB * NN * sizeof(float));
    u16* WhThi = (u16*)alloc((size_t)BB * FF * NN * 2);
    u16* WhTlo = (u16*)alloc((size_t)BB * FF * NN * 2);
    u16* A0hi = (u16*)alloc((size_t)K4 * NN * 2);
    u16* A0lo = (u16*)alloc((size_t)K4 * NN * 2);
    u16* A2hi = (u16*)alloc((size_t)NN * K4 * 2);
    u16* A2lo = (u16*)alloc((size_t)NN * K4 * 2);

    // per-batch chunk bytes: E hi/lo + S hi/lo + ADJ
    const size_t per_b = (size_t)NN * NN * 2 * 2 + (size_t)NN * K4 * 2 * 2 + (size_t)NN * NN * 4;
    int cb = 8;
    while (cb > 1 && ofs + (size_t)cb * per_b + 8192 > ws_size) cb >>= 1;
    u16* Ehi = (u16*)alloc((size_t)cb * NN * NN * 2);
    u16* Elo = (u16*)alloc((size_t)cb * NN * NN * 2);
    u16* Shi = (u16*)alloc((size_t)cb * NN * K4 * 2);
    u16* Slo = (u16*)alloc((size_t)cb * NN * K4 * 2);
    float* ADJ = (float*)alloc((size_t)cb * NN * NN * 4);

    k_u<<<1, 128, 0, stream>>>(W, a, u12);
    k_wh12<<<BB * NN, 128, 0, stream>>>(h, u12, Wh12);
    k_whT<<<dim3((BB * NN) / 64, FF / 64), 256, 0, stream>>>(W, h, WhThi, WhTlo);
    k_split<<<(K4 * NN / 4 + 255) / 256, 256, 0, stream>>>(A0, A0hi, A0lo, K4 * NN / 4);
    k_split<<<(NN * K4 / 4 + 255) / 256, 256, 0, stream>>>(A2, A2hi, A2lo, NN * K4 / 4);

    for (int c0 = 0; c0 < BB; c0 += cb) {
        int c = (BB - c0) < cb ? (BB - c0) : cb;
        k_e2<<<dim3(NN, c), 128, 0, stream>>>(Wh12, c0, Ehi, Elo);
        // S = sigmoid(E @ A0^T): M=512, N=2048, K=512
        k_mfma<0, NN><<<dim3(K4 / 128, NN / 128, c), 256, 0, stream>>>(
            Ehi, Elo, (long)NN * NN, A0hi, A0lo, 0, Shi, Slo, (long)NN * K4, K4, nullptr,
            nullptr, nullptr, nullptr);
        // adj = S @ A2^T + e; mask -> ADJ: M=512, N=512, K=2048
        k_mfma<1, K4><<<dim3(NN / 128, NN / 128, c), 256, 0, stream>>>(
            Shi, Slo, (long)NN * K4, A2hi, A2lo, 0, nullptr, nullptr, (long)NN * NN, NN, Ehi,
            Elo, ADJ, nullptr);
        k_softmax2<<<c * NN, 256, 0, stream>>>(ADJ, Ehi, Elo);
        // out = elu(att @ Wh): M=512, N=128, K=512
        k_mfma<2, NN><<<dim3(1, NN / 128, c), 256, 0, stream>>>(
            Ehi, Elo, (long)NN * NN, WhThi + (size_t)c0 * FF * NN, WhTlo + (size_t)c0 * FF * NN,
            (long)FF * NN, nullptr, nullptr, 0, 0, nullptr, nullptr, nullptr,
            out + (size_t)c0 * NN * FF);
    }
}

// Round 4
// 361.950 us; speedup vs baseline: 3.1007x; 3.1007x over previous
//
#include <hip/hip_runtime.h>

#define BB 32
#define NN 512
#define FF 128
#define K4 2048
#define ALPHA 0.2f
#define THRESH 0.6f
#define NEGINF -9e15f

typedef unsigned short u16;
typedef _Float16 f16;
typedef __attribute__((ext_vector_type(8))) _Float16 half8;
typedef __attribute__((ext_vector_type(4))) float f32x4;

union U16F { u16 u; f16 h; };
__device__ __forceinline__ u16 hbits(f16 h) { U16F x; x.h = h; return x.u; }
__device__ __forceinline__ float htof(u16 u) { U16F x; x.u = u; return (float)x.h; }
// fp16 hi/lo split: v ~= hi + lo, residual ~ 2^-22 |v|
__device__ __forceinline__ void split2(float v, u16& hi, u16& lo) {
    f16 h = (f16)v;
    f16 l = (f16)(v - (float)h);
    hi = hbits(h);
    lo = hbits(l);
}
__device__ __forceinline__ float lrelu(float x) { return x > 0.f ? x : ALPHA * x; }

__device__ __forceinline__ void gload16(const void* g, void* l) {
    __builtin_amdgcn_global_load_lds(
        (__attribute__((address_space(1))) const unsigned int*)(unsigned long long)g,
        (__attribute__((address_space(3))) unsigned int*)(unsigned int)(unsigned long long)l,
        16, 0, 0);
}

// u1[f] = sum_g W[g,f]*a[g];  u2[f] = sum_g W[g,f]*a[F+g]
__global__ void k_u(const float* __restrict__ W, const float* __restrict__ a,
                    float* __restrict__ u12) {
    int f = threadIdx.x;
    float s1 = 0.f, s2 = 0.f;
    for (int g = 0; g < FF; ++g) {
        float w = W[g * FF + f];
        s1 += w * a[g];
        s2 += w * a[FF + g];
    }
    u12[f] = s1;
    u12[FF + f] = s2;
}

// Wh1[row] = h[row,:]·u1 ; Wh2[row] = h[row,:]·u2
__global__ void k_wh12(const float* __restrict__ h, const float* __restrict__ u12,
                       float* __restrict__ Wh12) {
    int row = blockIdx.x;
    int f = threadIdx.x;  // 128
    float hv = h[(size_t)row * FF + f];
    float p1 = hv * u12[f], p2 = hv * u12[FF + f];
#pragma unroll
    for (int o = 1; o < 64; o <<= 1) {
        p1 += __shfl_xor(p1, o, 64);
        p2 += __shfl_xor(p2, o, 64);
    }
    __shared__ float s1[2], s2[2];
    int w = f >> 6;
    if ((f & 63) == 0) { s1[w] = p1; s2[w] = p2; }
    __syncthreads();
    if (f == 0) {
        Wh12[row] = s1[0] + s1[1];
        Wh12[BB * NN + row] = s2[0] + s2[1];
    }
}

// WhT[b][f][n] = (h@W^T)[b][n][f] split into fp16 hi/lo.
__global__ __launch_bounds__(256) void k_whT(const float* __restrict__ W,
                                             const float* __restrict__ h,
                                             u16* __restrict__ Thi, u16* __restrict__ Tlo) {
    const int bm = blockIdx.y * 64, bn = blockIdx.x * 64;
    __shared__ float As[32][68];
    __shared__ float Bs[32][68];
    int tid = threadIdx.x;
    int tx = tid & 15, ty = tid >> 4;
    float acc[4][4] = {{0.f}};
    int r = tid >> 3, q = tid & 7;
    const float* Ap = W + (size_t)(bm + r) * FF + q * 4;
    const float* Bp = h + (size_t)(bn + r) * FF + q * 4;
    for (int k0 = 0; k0 < FF; k0 += 32) {
        float4 a0 = *(const float4*)(Ap + k0);
        float4 a1 = *(const float4*)(Ap + k0 + 32 * FF);
        float4 b0 = *(const float4*)(Bp + k0);
        float4 b1 = *(const float4*)(Bp + k0 + 32 * FF);
        __syncthreads();
        As[q * 4 + 0][r] = a0.x; As[q * 4 + 1][r] = a0.y;
        As[q * 4 + 2][r] = a0.z; As[q * 4 + 3][r] = a0.w;
        As[q * 4 + 0][r + 32] = a1.x; As[q * 4 + 1][r + 32] = a1.y;
        As[q * 4 + 2][r + 32] = a1.z; As[q * 4 + 3][r + 32] = a1.w;
        Bs[q * 4 + 0][r] = b0.x; Bs[q * 4 + 1][r] = b0.y;
        Bs[q * 4 + 2][r] = b0.z; Bs[q * 4 + 3][r] = b0.w;
        Bs[q * 4 + 0][r + 32] = b1.x; Bs[q * 4 + 1][r + 32] = b1.y;
        Bs[q * 4 + 2][r + 32] = b1.z; Bs[q * 4 + 3][r + 32] = b1.w;
        __syncthreads();
#pragma unroll
        for (int kk = 0; kk < 32; ++kk) {
            float av[4], bv[4];
            *(float4*)av = *(const float4*)&As[kk][ty * 4];
            *(float4*)bv = *(const float4*)&Bs[kk][tx * 4];
#pragma unroll
            for (int i = 0; i < 4; ++i)
#pragma unroll
                for (int j = 0; j < 4; ++j) acc[i][j] = fmaf(av[i], bv[j], acc[i][j]);
        }
    }
#pragma unroll
    for (int i = 0; i < 4; ++i) {
        int f = bm + ty * 4 + i;
#pragma unroll
        for (int j = 0; j < 4; ++j) {
            int mg = bn + tx * 4 + j;
            u16 hi, lo;
            split2(acc[i][j], hi, lo);
            size_t idx = ((size_t)(mg >> 9) * FF + f) * NN + (mg & 511);
            Thi[idx] = hi;
            Tlo[idx] = lo;
        }
    }
}

// fp32 -> fp16 hi/lo split, vectorized
__global__ void k_split(const float* __restrict__ X, u16* __restrict__ Hi,
                        u16* __restrict__ Lo, int n4) {
    int i = blockIdx.x * 256 + threadIdx.x;
    if (i >= n4) return;
    float4 v = *(const float4*)(X + (size_t)i * 4);
    ushort4 hh, ll;
    split2(v.x, hh.x, ll.x);
    split2(v.y, hh.y, ll.y);
    split2(v.z, hh.z, ll.z);
    split2(v.w, hh.w, ll.w);
    *(ushort4*)(Hi + (size_t)i * 4) = hh;
    *(ushort4*)(Lo + (size_t)i * 4) = ll;
}

// E chunk: e[b,i,j] = lrelu(Wh1[b,i] + Wh2[b,j]) -> fp16 hi/lo
__global__ void k_e2(const float* __restrict__ Wh12, int c0, u16* __restrict__ Ehi,
                     u16* __restrict__ Elo) {
    const int i = blockIdx.x;
    const int bl = blockIdx.y;
    const int b = c0 + bl;
    const int t = threadIdx.x;  // 128
    const float w1 = Wh12[b * NN + i];
    const float* w2 = Wh12 + BB * NN + b * NN;
    const int j = t * 4;
    float4 v = *(const float4*)(w2 + j);
    ushort4 hh, ll;
    split2(lrelu(w1 + v.x), hh.x, ll.x);
    split2(lrelu(w1 + v.y), hh.y, ll.y);
    split2(lrelu(w1 + v.z), hh.z, ll.z);
    split2(lrelu(w1 + v.w), hh.w, ll.w);
    const size_t idx = ((size_t)bl * NN + i) * NN + j;
    *(ushort4*)(Ehi + idx) = hh;
    *(ushort4*)(Elo + idx) = ll;
}

// Split-fp16 MFMA GEMM, fused 3-term, depth-2 pipelined.
// C[m,n] = epi( sum_k (Ahi+Alo)[m,k]*(Bhi+Blo)[n,k] ), dropping lo*lo (~2^-22 rel).
// 128x128 tile, 4 waves (2x2). LDS: 2 bufs x {Ahi,Alo,Bhi,Blo} x 128x32 fp16 = 64KB.
template <int EPI, int K>
__global__ __launch_bounds__(256) void k_mfma(
    const u16* __restrict__ Ahi, const u16* __restrict__ Alo, long sA,
    const u16* __restrict__ Bhi, const u16* __restrict__ Blo, long sB,
    u16* __restrict__ Chi, u16* __restrict__ Clo, long sC, int ldc,
    const u16* __restrict__ Eh, const u16* __restrict__ El, float* __restrict__ ADJ,
    float* __restrict__ OUT) {
    __shared__ __align__(16) u16 lds[2][4][4096];
    const int tid = threadIdx.x;
    const int l = tid & 63, w = tid >> 6;
    const int wr = w >> 1, wc = w & 1;
    const int bz = blockIdx.z;
    const int bm = blockIdx.y * 128, bn = blockIdx.x * 128;

    const u16* A0p = Ahi + (size_t)bz * sA;
    const u16* A1p = Alo + (size_t)bz * sA;
    const u16* B0p = Bhi + (size_t)bz * sB;
    const u16* B1p = Blo + (size_t)bz * sB;

    const int g0 = w, g1 = w + 4;
    const size_t offA0 = (size_t)(bm + g0 * 16 + (l & 15)) * K + (l >> 4) * 8;
    const size_t offA1 = (size_t)(bm + g1 * 16 + (l & 15)) * K + (l >> 4) * 8;
    const size_t offB0 = (size_t)(bn + g0 * 16 + (l & 15)) * K + (l >> 4) * 8;
    const size_t offB1 = (size_t)(bn + g1 * 16 + (l & 15)) * K + (l >> 4) * 8;

    auto STAGE = [&](int buf, int kk) {
        gload16(A0p + offA0 + kk, &lds[buf][0][g0 * 512]);
        gload16(A0p + offA1 + kk, &lds[buf][0][g1 * 512]);
        gload16(A1p + offA0 + kk, &lds[buf][1][g0 * 512]);
        gload16(A1p + offA1 + kk, &lds[buf][1][g1 * 512]);
        gload16(B0p + offB0 + kk, &lds[buf][2][g0 * 512]);
        gload16(B0p + offB1 + kk, &lds[buf][2][g1 * 512]);
        gload16(B1p + offB0 + kk, &lds[buf][3][g0 * 512]);
        gload16(B1p + offB1 + kk, &lds[buf][3][g1 * 512]);
    };

    f32x4 acc[4][4];
#pragma unroll
    for (int m = 0; m < 4; ++m)
#pragma unroll
        for (int n = 0; n < 4; ++n) acc[m][n] = (f32x4){0.f, 0.f, 0.f, 0.f};

    constexpr int NT = K / 32;
    STAGE(0, 0);
    for (int t = 0; t < NT; ++t) {
        const int cur = t & 1;
        if (t + 1 < NT) {
            STAGE(cur ^ 1, (t + 1) * 32);
            asm volatile("s_waitcnt vmcnt(8)" ::: "memory");
        } else {
            asm volatile("s_waitcnt vmcnt(0)" ::: "memory");
        }
        __builtin_amdgcn_s_barrier();
        __builtin_amdgcn_sched_barrier(0);
        half8 ah[4], al[4], bh[4], bl[4];
#pragma unroll
        for (int m = 0; m < 4; ++m) {
            ah[m] = *(const half8*)&lds[cur][0][((wr * 4 + m) * 64 + l) * 8];
            al[m] = *(const half8*)&lds[cur][1][((wr * 4 + m) * 64 + l) * 8];
        }
#pragma unroll
        for (int n = 0; n < 4; ++n) {
            bh[n] = *(const half8*)&lds[cur][2][((wc * 4 + n) * 64 + l) * 8];
            bl[n] = *(const half8*)&lds[cur][3][((wc * 4 + n) * 64 + l) * 8];
        }
#pragma unroll
        for (int m = 0; m < 4; ++m)
#pragma unroll
            for (int n = 0; n < 4; ++n) {
                acc[m][n] =
                    __builtin_amdgcn_mfma_f32_16x16x32_f16(ah[m], bh[n], acc[m][n], 0, 0, 0);
                acc[m][n] =
                    __builtin_amdgcn_mfma_f32_16x16x32_f16(al[m], bh[n], acc[m][n], 0, 0, 0);
                acc[m][n] =
                    __builtin_amdgcn_mfma_f32_16x16x32_f16(ah[m], bl[n], acc[m][n], 0, 0, 0);
            }
        __builtin_amdgcn_s_barrier();
    }

    const int lr = (l >> 4) * 4, lc = l & 15;
#pragma unroll
    for (int m = 0; m < 4; ++m) {
#pragma unroll
        for (int n = 0; n < 4; ++n) {
#pragma unroll
            for (int j = 0; j < 4; ++j) {
                const int row = bm + wr * 64 + m * 16 + lr + j;
                const int col = bn + wc * 64 + n * 16 + lc;
                const float v = acc[m][n][j];
                if constexpr (EPI == 0) {
                    const float s = 1.f / (1.f + expf(-v));
                    u16 hi, lo;
                    split2(s, hi, lo);
                    const size_t idx = (size_t)bz * sC + (size_t)row * ldc + col;
                    Chi[idx] = hi;
                    Clo[idx] = lo;
                } else if constexpr (EPI == 1) {
                    const size_t idx = (size_t)bz * sC + (size_t)row * ldc + col;
                    const float e = htof(Eh[idx]) + htof(El[idx]);
                    ADJ[idx] = (e + v > THRESH) ? e : NEGINF;
                } else {
                    const size_t idx = (size_t)bz * (size_t)(NN * FF) + (size_t)row * FF + col;
                    OUT[idx] = v > 0.f ? v : expf(v) - 1.f;
                }
            }
        }
    }
}

// softmax rows of ADJ (fp32), write att as fp16 hi/lo (into freed E buffers)
__global__ __launch_bounds__(256) void k_softmax2(const float* __restrict__ ADJ,
                                                  u16* __restrict__ Hi, u16* __restrict__ Lo) {
    const size_t row = blockIdx.x;
    const float* p = ADJ + row * NN;
    const int t = threadIdx.x;
    float v0 = p[t], v1 = p[t + 256];
    float m = fmaxf(v0, v1);
#pragma unroll
    for (int o = 1; o < 64; o <<= 1) m = fmaxf(m, __shfl_xor(m, o, 64));
    __shared__ float red[4], red2[4];
    int w = t >> 6;
    if ((t & 63) == 0) red[w] = m;
    __syncthreads();
    m = fmaxf(fmaxf(red[0], red[1]), fmaxf(red[2], red[3]));
    float e0 = __expf(v0 - m), e1 = __expf(v1 - m);
    float s = e0 + e1;
#pragma unroll
    for (int o = 1; o < 64; o <<= 1) s += __shfl_xor(s, o, 64);
    if ((t & 63) == 0) red2[w] = s;
    __syncthreads();
    s = red2[0] + red2[1] + red2[2] + red2[3];
    float inv = 1.f / s;
    float a0 = e0 * inv, a1 = e1 * inv;
    u16 h0, l0, h1, l1;
    split2(a0, h0, l0);
    split2(a1, h1, l1);
    Hi[row * NN + t] = h0;
    Hi[row * NN + t + 256] = h1;
    Lo[row * NN + t] = l0;
    Lo[row * NN + t + 256] = l1;
}

extern "C" void kernel_launch(void* const* d_in, const int* in_sizes, int n_in,
                              void* d_out, int out_size, void* d_ws, size_t ws_size,
                              hipStream_t stream) {
    const float* h = (const float*)d_in[0];
    const float* W = (const float*)d_in[1];
    const float* a = (const float*)d_in[2];
    const float* A0 = (const float*)d_in[3];
    const float* A2 = (const float*)d_in[4];
    float* out = (float*)d_out;

    char* ws = (char*)d_ws;
    size_t ofs = 0;
    auto alloc = [&](size_t bytes) -> void* {
        void* p = ws + ofs;
        ofs = (ofs + bytes + 255) & ~(size_t)255;
        return p;
    };
    float* u12 = (float*)alloc(2 * FF * sizeof(float));
    float* Wh12 = (float*)alloc(2 * (size_t)BB * NN * sizeof(float));
    u16* WhThi = (u16*)alloc((size_t)BB * FF * NN * 2);
    u16* WhTlo = (u16*)alloc((size_t)BB * FF * NN * 2);
    u16* A0hi = (u16*)alloc((size_t)K4 * NN * 2);
    u16* A0lo = (u16*)alloc((size_t)K4 * NN * 2);
    u16* A2hi = (u16*)alloc((size_t)NN * K4 * 2);
    u16* A2lo = (u16*)alloc((size_t)NN * K4 * 2);

    // per-batch chunk bytes: E hi/lo + S hi/lo + ADJ
    const size_t per_b = (size_t)NN * NN * 2 * 2 + (size_t)NN * K4 * 2 * 2 + (size_t)NN * NN * 4;
    int cb = BB;
    while (cb > 1 && ofs + (size_t)cb * per_b + 8192 > ws_size) cb >>= 1;
    u16* Ehi = (u16*)alloc((size_t)cb * NN * NN * 2);
    u16* Elo = (u16*)alloc((size_t)cb * NN * NN * 2);
    u16* Shi = (u16*)alloc((size_t)cb * NN * K4 * 2);
    u16* Slo = (u16*)alloc((size_t)cb * NN * K4 * 2);
    float* ADJ = (float*)alloc((size_t)cb * NN * NN * 4);

    k_u<<<1, 128, 0, stream>>>(W, a, u12);
    k_wh12<<<BB * NN, 128, 0, stream>>>(h, u12, Wh12);
    k_whT<<<dim3((BB * NN) / 64, FF / 64), 256, 0, stream>>>(W, h, WhThi, WhTlo);
    k_split<<<(K4 * NN / 4 + 255) / 256, 256, 0, stream>>>(A0, A0hi, A0lo, K4 * NN / 4);
    k_split<<<(NN * K4 / 4 + 255) / 256, 256, 0, stream>>>(A2, A2hi, A2lo, NN * K4 / 4);

    for (int c0 = 0; c0 < BB; c0 += cb) {
        int c = (BB - c0) < cb ? (BB - c0) : cb;
        k_e2<<<dim3(NN, c), 128, 0, stream>>>(Wh12, c0, Ehi, Elo);
        // S = sigmoid(E @ A0^T): M=512, N=2048, K=512
        k_mfma<0, NN><<<dim3(K4 / 128, NN / 128, c), 256, 0, stream>>>(
            Ehi, Elo, (long)NN * NN, A0hi, A0lo, 0, Shi, Slo, (long)NN * K4, K4, nullptr,
            nullptr, nullptr, nullptr);
        // adj = S @ A2^T + e; mask -> ADJ: M=512, N=512, K=2048
        k_mfma<1, K4><<<dim3(NN / 128, NN / 128, c), 256, 0, stream>>>(
            Shi, Slo, (long)NN * K4, A2hi, A2lo, 0, nullptr, nullptr, (long)NN * NN, NN, Ehi,
            Elo, ADJ, nullptr);
        k_softmax2<<<c * NN, 256, 0, stream>>>(ADJ, Ehi, Elo);
        // out = elu(att @ Wh): M=512, N=128, K=512
        k_mfma<2, NN><<<dim3(1, NN / 128, c), 256, 0, stream>>>(
            Ehi, Elo, (long)NN * NN, WhThi + (size_t)c0 * FF * NN, WhTlo + (size_t)c0 * FF * NN,
            (long)FF * NN, nullptr, nullptr, 0, 0, nullptr, nullptr, nullptr,
            out + (size_t)c0 * NN * FF);
    }
}

// Round 5
// 292.160 us; speedup vs baseline: 3.8414x; 1.2389x over previous
//
#include <hip/hip_runtime.h>

#define BB 32
#define NN 512
#define FF 128
#define K4 2048
#define ALPHA 0.2f
#define THRESH 0.6f
#define NEGINF -9e15f

typedef unsigned short u16;
typedef unsigned int u32;
typedef _Float16 f16;
typedef __attribute__((ext_vector_type(8))) _Float16 half8;
typedef __attribute__((ext_vector_type(4))) float f32x4;

union U16F { u16 u; f16 h; };
__device__ __forceinline__ u16 hbits(f16 h) { U16F x; x.h = h; return x.u; }
__device__ __forceinline__ float htof(u16 u) { U16F x; x.u = u; return (float)x.h; }
__device__ __forceinline__ void split2(float v, u16& hi, u16& lo) {
    f16 h = (f16)v;
    f16 l = (f16)(v - (float)h);
    hi = hbits(h);
    lo = hbits(l);
}
__device__ __forceinline__ float lrelu(float x) { return x > 0.f ? x : ALPHA * x; }

__device__ __forceinline__ void gload16(const void* g, void* l) {
    __builtin_amdgcn_global_load_lds(
        (__attribute__((address_space(1))) const unsigned int*)(unsigned long long)g,
        (__attribute__((address_space(3))) unsigned int*)(unsigned int)(unsigned long long)l,
        16, 0, 0);
}

// u1[f] = sum_g W[g,f]*a[g];  u2[f] = sum_g W[g,f]*a[F+g]
__global__ void k_u(const float* __restrict__ W, const float* __restrict__ a,
                    float* __restrict__ u12) {
    int f = threadIdx.x;
    float s1 = 0.f, s2 = 0.f;
    for (int g = 0; g < FF; ++g) {
        float w = W[g * FF + f];
        s1 += w * a[g];
        s2 += w * a[FF + g];
    }
    u12[f] = s1;
    u12[FF + f] = s2;
}

// Wh1[row] = h[row,:]·u1 ; Wh2[row] = h[row,:]·u2   (flat row = b*N+n)
__global__ void k_wh12(const float* __restrict__ h, const float* __restrict__ u12,
                       float* __restrict__ Wh12) {
    int row = blockIdx.x;
    int f = threadIdx.x;  // 128
    float hv = h[(size_t)row * FF + f];
    float p1 = hv * u12[f], p2 = hv * u12[FF + f];
#pragma unroll
    for (int o = 1; o < 64; o <<= 1) {
        p1 += __shfl_xor(p1, o, 64);
        p2 += __shfl_xor(p2, o, 64);
    }
    __shared__ float s1[2], s2[2];
    int w = f >> 6;
    if ((f & 63) == 0) { s1[w] = p1; s2[w] = p2; }
    __syncthreads();
    if (f == 0) {
        Wh12[row] = s1[0] + s1[1];
        Wh12[BB * NN + row] = s2[0] + s2[1];
    }
}

// WhT[b][f][n] = (h@W^T)[b][n][f] split into fp16 hi/lo (PV's B operand).
__global__ __launch_bounds__(256) void k_whT(const float* __restrict__ W,
                                             const float* __restrict__ h,
                                             u16* __restrict__ Thi, u16* __restrict__ Tlo) {
    const int bm = blockIdx.y * 64, bn = blockIdx.x * 64;
    __shared__ float As[32][68];
    __shared__ float Bs[32][68];
    int tid = threadIdx.x;
    int tx = tid & 15, ty = tid >> 4;
    float acc[4][4] = {{0.f}};
    int r = tid >> 3, q = tid & 7;
    const float* Ap = W + (size_t)(bm + r) * FF + q * 4;
    const float* Bp = h + (size_t)(bn + r) * FF + q * 4;
    for (int k0 = 0; k0 < FF; k0 += 32) {
        float4 a0 = *(const float4*)(Ap + k0);
        float4 a1 = *(const float4*)(Ap + k0 + 32 * FF);
        float4 b0 = *(const float4*)(Bp + k0);
        float4 b1 = *(const float4*)(Bp + k0 + 32 * FF);
        __syncthreads();
        As[q * 4 + 0][r] = a0.x; As[q * 4 + 1][r] = a0.y;
        As[q * 4 + 2][r] = a0.z; As[q * 4 + 3][r] = a0.w;
        As[q * 4 + 0][r + 32] = a1.x; As[q * 4 + 1][r + 32] = a1.y;
        As[q * 4 + 2][r + 32] = a1.z; As[q * 4 + 3][r + 32] = a1.w;
        Bs[q * 4 + 0][r] = b0.x; Bs[q * 4 + 1][r] = b0.y;
        Bs[q * 4 + 2][r] = b0.z; Bs[q * 4 + 3][r] = b0.w;
        Bs[q * 4 + 0][r + 32] = b1.x; Bs[q * 4 + 1][r + 32] = b1.y;
        Bs[q * 4 + 2][r + 32] = b1.z; Bs[q * 4 + 3][r + 32] = b1.w;
        __syncthreads();
#pragma unroll
        for (int kk = 0; kk < 32; ++kk) {
            float av[4], bv[4];
            *(float4*)av = *(const float4*)&As[kk][ty * 4];
            *(float4*)bv = *(const float4*)&Bs[kk][tx * 4];
#pragma unroll
            for (int i = 0; i < 4; ++i)
#pragma unroll
                for (int j = 0; j < 4; ++j) acc[i][j] = fmaf(av[i], bv[j], acc[i][j]);
        }
    }
#pragma unroll
    for (int i = 0; i < 4; ++i) {
        int f = bm + ty * 4 + i;
#pragma unroll
        for (int j = 0; j < 4; ++j) {
            int mg = bn + tx * 4 + j;
            u16 hi, lo;
            split2(acc[i][j], hi, lo);
            size_t idx = ((size_t)(mg >> 9) * FF + f) * NN + (mg & 511);
            Thi[idx] = hi;
            Tlo[idx] = lo;
        }
    }
}

// fp32 -> fp16 hi/lo split, vectorized
__global__ void k_split(const float* __restrict__ X, u16* __restrict__ Hi,
                        u16* __restrict__ Lo, int n4) {
    int i = blockIdx.x * 256 + threadIdx.x;
    if (i >= n4) return;
    float4 v = *(const float4*)(X + (size_t)i * 4);
    ushort4 hh, ll;
    split2(v.x, hh.x, ll.x);
    split2(v.y, hh.y, ll.y);
    split2(v.z, hh.z, ll.z);
    split2(v.w, hh.w, ll.w);
    *(ushort4*)(Hi + (size_t)i * 4) = hh;
    *(ushort4*)(Lo + (size_t)i * 4) = ll;
}

// GEMM1: S = sigmoid(E @ A0^T), E generated on the fly from Wh12.
// Flattened M = c*512, N = 2048, K = 512. Tile 256x256, BK=32, 8 waves.
// LDS: 2 bufs x {Ahi,Alo,Bhi,Blo} x 256x32 fp16 = 128 KB. A generated (VALU),
// B staged via global_load_lds (4 wave-loads/wave/K-step), depth-2, vmcnt(4).
__global__ __launch_bounds__(512, 2) void k_g1(const float* __restrict__ Wh12, int c0,
                                               const u16* __restrict__ Bhi,
                                               const u16* __restrict__ Blo,
                                               u16* __restrict__ Shi, u16* __restrict__ Slo,
                                               int mblocks) {
    __shared__ __align__(16) u16 lds[2][4][8192];
    __shared__ float wh1s[256];
    __shared__ float wh2s[512];
    const int tid = threadIdx.x;
    const int l = tid & 63, w = tid >> 6;
    // XCD-chunked swizzle (nwg % 8 == 0 always): contiguous m-range per XCD, same n.
    const int nwg = gridDim.x, q = nwg >> 3;
    const int wg = (blockIdx.x & 7) * q + (blockIdx.x >> 3);
    const int nb = wg / mblocks, mb = wg % mblocks;
    const int bm = mb * 256, bn = nb * 256;
    const int bglob = c0 + (bm >> 9);

    // preload Wh rows
    if (tid < 256) wh1s[tid] = Wh12[(size_t)c0 * NN + bm + tid];
    wh2s[tid] = Wh12[BB * NN + (size_t)bglob * NN + tid];
    if (tid + 512 < 512) {}
    __syncthreads();

    auto GEN_A = [&](int buf, int k0) {
#pragma unroll
        for (int cc = 0; cc < 2; ++cc) {
            const int c = tid + cc * 512;
            const int row = ((c >> 6) << 4) + (c & 15);
            const int kc = k0 + ((c >> 4) & 3) * 8;
            const float w1 = wh1s[row];
            u32 hh[4], llv[4];
#pragma unroll
            for (int jj = 0; jj < 4; ++jj) {
                float e0 = lrelu(w1 + wh2s[kc + 2 * jj]);
                float e1 = lrelu(w1 + wh2s[kc + 2 * jj + 1]);
                u16 h0, l0, h1, l1;
                split2(e0, h0, l0);
                split2(e1, h1, l1);
                hh[jj] = (u32)h0 | ((u32)h1 << 16);
                llv[jj] = (u32)l0 | ((u32)l1 << 16);
            }
            *(uint4*)&lds[buf][0][c * 8] = make_uint4(hh[0], hh[1], hh[2], hh[3]);
            *(uint4*)&lds[buf][1][c * 8] = make_uint4(llv[0], llv[1], llv[2], llv[3]);
        }
    };
    auto STAGE_B = [&](int buf, int k0) {
#pragma unroll
        for (int i = 0; i < 2; ++i) {
            const int g = w * 2 + i;
            const size_t ro = (size_t)(bn + g * 16 + (l & 15)) * NN + k0 + ((l >> 4) * 8);
            gload16(Bhi + ro, &lds[buf][2][g * 512]);
            gload16(Blo + ro, &lds[buf][3][g * 512]);
        }
    };

    f32x4 acc[8][4];
#pragma unroll
    for (int m = 0; m < 8; ++m)
#pragma unroll
        for (int n = 0; n < 4; ++n) acc[m][n] = (f32x4){0.f, 0.f, 0.f, 0.f};

    GEN_A(0, 0);
    STAGE_B(0, 0);
    for (int t = 0; t < 16; ++t) {
        const int cur = t & 1;
        if (t < 15) {
            GEN_A(cur ^ 1, (t + 1) * 32);
            STAGE_B(cur ^ 1, (t + 1) * 32);
            asm volatile("s_waitcnt vmcnt(4)" ::: "memory");
        } else {
            asm volatile("s_waitcnt vmcnt(0)" ::: "memory");
        }
        asm volatile("s_waitcnt lgkmcnt(0)" ::: "memory");
        __builtin_amdgcn_s_barrier();
        __builtin_amdgcn_sched_barrier(0);
        half8 bh[4], bl[4];
#pragma unroll
        for (int n = 0; n < 4; ++n) {
            const int gB = (w & 3) * 4 + n;
            bh[n] = *(const half8*)&lds[cur][2][(gB * 64 + l) * 8];
            bl[n] = *(const half8*)&lds[cur][3][(gB * 64 + l) * 8];
        }
        __builtin_amdgcn_s_setprio(1);
#pragma unroll
        for (int m = 0; m < 8; ++m) {
            const int gA = (w >> 2) * 8 + m;
            half8 ah = *(const half8*)&lds[cur][0][(gA * 64 + l) * 8];
            half8 al = *(const half8*)&lds[cur][1][(gA * 64 + l) * 8];
#pragma unroll
            for (int n = 0; n < 4; ++n) {
                acc[m][n] =
                    __builtin_amdgcn_mfma_f32_16x16x32_f16(ah, bh[n], acc[m][n], 0, 0, 0);
                acc[m][n] =
                    __builtin_amdgcn_mfma_f32_16x16x32_f16(al, bh[n], acc[m][n], 0, 0, 0);
                acc[m][n] =
                    __builtin_amdgcn_mfma_f32_16x16x32_f16(ah, bl[n], acc[m][n], 0, 0, 0);
            }
        }
        __builtin_amdgcn_s_setprio(0);
        __builtin_amdgcn_sched_barrier(0);
        __builtin_amdgcn_s_barrier();
    }

    const int lr = (l >> 4) * 4, lc = l & 15;
#pragma unroll
    for (int m = 0; m < 8; ++m) {
#pragma unroll
        for (int n = 0; n < 4; ++n) {
#pragma unroll
            for (int j = 0; j < 4; ++j) {
                const int row = bm + (w >> 2) * 128 + m * 16 + lr + j;
                const int col = bn + (w & 3) * 64 + n * 16 + lc;
                const float s = 1.f / (1.f + expf(-acc[m][n][j]));
                u16 hi, lo;
                split2(s, hi, lo);
                const size_t idx = (size_t)row * K4 + col;
                Shi[idx] = hi;
                Slo[idx] = lo;
            }
        }
    }
}

// GEMM2: adj = S @ A2^T + e; mask -> packed ADJ (u32: lo<<16|hi of e, or ~0 if cut).
// Flattened M = c*512, N = 512, K = 2048. Tile 128x256, BK=32, 8 waves, 96 KB LDS.
__global__ __launch_bounds__(512, 2) void k_g2(const u16* __restrict__ Ahi,
                                               const u16* __restrict__ Alo,
                                               const u16* __restrict__ Bhi,
                                               const u16* __restrict__ Blo,
                                               const float* __restrict__ Wh12, int c0,
                                               u32* __restrict__ ADJ, int mblocks) {
    __shared__ __align__(16) u16 ldsA[2][2][4096];
    __shared__ __align__(16) u16 ldsB[2][2][8192];
    const int tid = threadIdx.x;
    const int l = tid & 63, w = tid >> 6;
    const int nwg = gridDim.x, q = nwg >> 3;
    const int wg = (blockIdx.x & 7) * q + (blockIdx.x >> 3);
    const int nb = wg / mblocks, mb = wg % mblocks;
    const int bm = mb * 128, bn = nb * 256;

    auto STAGE = [&](int buf, int k0) {
        const size_t ra = (size_t)(bm + w * 16 + (l & 15)) * K4 + k0 + ((l >> 4) * 8);
        gload16(Ahi + ra, &ldsA[buf][0][w * 512]);
        gload16(Alo + ra, &ldsA[buf][1][w * 512]);
#pragma unroll
        for (int i = 0; i < 2; ++i) {
            const int g = w * 2 + i;
            const size_t rb = (size_t)(bn + g * 16 + (l & 15)) * K4 + k0 + ((l >> 4) * 8);
            gload16(Bhi + rb, &ldsB[buf][0][g * 512]);
            gload16(Blo + rb, &ldsB[buf][1][g * 512]);
        }
    };

    f32x4 acc[4][4];
#pragma unroll
    for (int m = 0; m < 4; ++m)
#pragma unroll
        for (int n = 0; n < 4; ++n) acc[m][n] = (f32x4){0.f, 0.f, 0.f, 0.f};

    STAGE(0, 0);
    for (int t = 0; t < 64; ++t) {
        const int cur = t & 1;
        if (t < 63) {
            STAGE(cur ^ 1, (t + 1) * 32);
            asm volatile("s_waitcnt vmcnt(6)" ::: "memory");
        } else {
            asm volatile("s_waitcnt vmcnt(0)" ::: "memory");
        }
        __builtin_amdgcn_s_barrier();
        __builtin_amdgcn_sched_barrier(0);
        half8 bh[4], bl[4];
#pragma unroll
        for (int n = 0; n < 4; ++n) {
            const int gB = (w & 3) * 4 + n;
            bh[n] = *(const half8*)&ldsB[cur][0][(gB * 64 + l) * 8];
            bl[n] = *(const half8*)&ldsB[cur][1][(gB * 64 + l) * 8];
        }
        __builtin_amdgcn_s_setprio(1);
#pragma unroll
        for (int m = 0; m < 4; ++m) {
            const int gA = (w >> 2) * 4 + m;
            half8 ah = *(const half8*)&ldsA[cur][0][(gA * 64 + l) * 8];
            half8 al = *(const half8*)&ldsA[cur][1][(gA * 64 + l) * 8];
#pragma unroll
            for (int n = 0; n < 4; ++n) {
                acc[m][n] =
                    __builtin_amdgcn_mfma_f32_16x16x32_f16(ah, bh[n], acc[m][n], 0, 0, 0);
                acc[m][n] =
                    __builtin_amdgcn_mfma_f32_16x16x32_f16(al, bh[n], acc[m][n], 0, 0, 0);
                acc[m][n] =
                    __builtin_amdgcn_mfma_f32_16x16x32_f16(ah, bl[n], acc[m][n], 0, 0, 0);
            }
        }
        __builtin_amdgcn_s_setprio(0);
        __builtin_amdgcn_sched_barrier(0);
        __builtin_amdgcn_s_barrier();
    }

    const int bglob = c0 + (bm >> 9);
    const float* wh2p = Wh12 + BB * NN + (size_t)bglob * NN;
    const int lr = (l >> 4) * 4, lc = l & 15;
#pragma unroll
    for (int m = 0; m < 4; ++m) {
#pragma unroll
        for (int n = 0; n < 4; ++n) {
#pragma unroll
            for (int j = 0; j < 4; ++j) {
                const int row = bm + (w >> 2) * 64 + m * 16 + lr + j;
                const int col = bn + (w & 3) * 64 + n * 16 + lc;
                const float e = lrelu(Wh12[(size_t)c0 * NN + row] + wh2p[col]);
                u32 pk = 0xFFFFFFFFu;
                if (e + acc[m][n][j] > THRESH) {
                    u16 hi, lo;
                    split2(e, hi, lo);
                    pk = (u32)hi | ((u32)lo << 16);
                }
                ADJ[(size_t)row * NN + col] = pk;
            }
        }
    }
}

// softmax rows of packed ADJ, write att as fp16 hi/lo
__global__ __launch_bounds__(256) void k_softmax2(const u32* __restrict__ ADJ,
                                                  u16* __restrict__ Hi, u16* __restrict__ Lo) {
    const size_t row = blockIdx.x;
    const u32* p = ADJ + row * NN;
    const int t = threadIdx.x;
    u32 w0 = p[t], w1 = p[t + 256];
    float v0 = (w0 == 0xFFFFFFFFu) ? NEGINF : htof((u16)(w0 & 0xFFFF)) + htof((u16)(w0 >> 16));
    float v1 = (w1 == 0xFFFFFFFFu) ? NEGINF : htof((u16)(w1 & 0xFFFF)) + htof((u16)(w1 >> 16));
    float m = fmaxf(v0, v1);
#pragma unroll
    for (int o = 1; o < 64; o <<= 1) m = fmaxf(m, __shfl_xor(m, o, 64));
    __shared__ float red[4], red2[4];
    int w = t >> 6;
    if ((t & 63) == 0) red[w] = m;
    __syncthreads();
    m = fmaxf(fmaxf(red[0], red[1]), fmaxf(red[2], red[3]));
    float e0 = __expf(v0 - m), e1 = __expf(v1 - m);
    float s = e0 + e1;
#pragma unroll
    for (int o = 1; o < 64; o <<= 1) s += __shfl_xor(s, o, 64);
    if ((t & 63) == 0) red2[w] = s;
    __syncthreads();
    s = red2[0] + red2[1] + red2[2] + red2[3];
    float inv = 1.f / s;
    float a0 = e0 * inv, a1 = e1 * inv;
    u16 h0, l0, h1, l1;
    split2(a0, h0, l0);
    split2(a1, h1, l1);
    Hi[row * NN + t] = h0;
    Hi[row * NN + t + 256] = h1;
    Lo[row * NN + t] = l0;
    Lo[row * NN + t + 256] = l1;
}

// PV: out = elu(att @ Wh) — round-4 proven structure, batched, 128x128 tile.
__global__ __launch_bounds__(256) void k_pv(const u16* __restrict__ Ahi,
                                            const u16* __restrict__ Alo,
                                            const u16* __restrict__ Bhi,
                                            const u16* __restrict__ Blo,
                                            float* __restrict__ OUT) {
    __shared__ __align__(16) u16 lds[2][4][4096];
    const int tid = threadIdx.x;
    const int l = tid & 63, w = tid >> 6;
    const int wr = w >> 1, wc = w & 1;
    const int bz = blockIdx.z;
    const int bm = blockIdx.y * 128, bn = 0;

    const u16* A0p = Ahi + (size_t)bz * NN * NN;
    const u16* A1p = Alo + (size_t)bz * NN * NN;
    const u16* B0p = Bhi + (size_t)bz * FF * NN;
    const u16* B1p = Blo + (size_t)bz * FF * NN;

    const int g0 = w, g1 = w + 4;
    const size_t offA0 = (size_t)(bm + g0 * 16 + (l & 15)) * NN + (l >> 4) * 8;
    const size_t offA1 = (size_t)(bm + g1 * 16 + (l & 15)) * NN + (l >> 4) * 8;
    const size_t offB0 = (size_t)(bn + g0 * 16 + (l & 15)) * NN + (l >> 4) * 8;
    const size_t offB1 = (size_t)(bn + g1 * 16 + (l & 15)) * NN + (l >> 4) * 8;

    auto STAGE = [&](int buf, int kk) {
        gload16(A0p + offA0 + kk, &lds[buf][0][g0 * 512]);
        gload16(A0p + offA1 + kk, &lds[buf][0][g1 * 512]);
        gload16(A1p + offA0 + kk, &lds[buf][1][g0 * 512]);
        gload16(A1p + offA1 + kk, &lds[buf][1][g1 * 512]);
        gload16(B0p + offB0 + kk, &lds[buf][2][g0 * 512]);
        gload16(B0p + offB1 + kk, &lds[buf][2][g1 * 512]);
        gload16(B1p + offB0 + kk, &lds[buf][3][g0 * 512]);
        gload16(B1p + offB1 + kk, &lds[buf][3][g1 * 512]);
    };

    f32x4 acc[4][4];
#pragma unroll
    for (int m = 0; m < 4; ++m)
#pragma unroll
        for (int n = 0; n < 4; ++n) acc[m][n] = (f32x4){0.f, 0.f, 0.f, 0.f};

    STAGE(0, 0);
    for (int t = 0; t < 16; ++t) {
        const int cur = t & 1;
        if (t + 1 < 16) {
            STAGE(cur ^ 1, (t + 1) * 32);
            asm volatile("s_waitcnt vmcnt(8)" ::: "memory");
        } else {
            asm volatile("s_waitcnt vmcnt(0)" ::: "memory");
        }
        __builtin_amdgcn_s_barrier();
        __builtin_amdgcn_sched_barrier(0);
        half8 ah[4], al[4], bh[4], bl[4];
#pragma unroll
        for (int m = 0; m < 4; ++m) {
            ah[m] = *(const half8*)&lds[cur][0][((wr * 4 + m) * 64 + l) * 8];
            al[m] = *(const half8*)&lds[cur][1][((wr * 4 + m) * 64 + l) * 8];
        }
#pragma unroll
        for (int n = 0; n < 4; ++n) {
            bh[n] = *(const half8*)&lds[cur][2][((wc * 4 + n) * 64 + l) * 8];
            bl[n] = *(const half8*)&lds[cur][3][((wc * 4 + n) * 64 + l) * 8];
        }
#pragma unroll
        for (int m = 0; m < 4; ++m)
#pragma unroll
            for (int n = 0; n < 4; ++n) {
                acc[m][n] =
                    __builtin_amdgcn_mfma_f32_16x16x32_f16(ah[m], bh[n], acc[m][n], 0, 0, 0);
                acc[m][n] =
                    __builtin_amdgcn_mfma_f32_16x16x32_f16(al[m], bh[n], acc[m][n], 0, 0, 0);
                acc[m][n] =
                    __builtin_amdgcn_mfma_f32_16x16x32_f16(ah[m], bl[n], acc[m][n], 0, 0, 0);
            }
        __builtin_amdgcn_s_barrier();
    }

    const int lr = (l >> 4) * 4, lc = l & 15;
#pragma unroll
    for (int m = 0; m < 4; ++m) {
#pragma unroll
        for (int n = 0; n < 4; ++n) {
#pragma unroll
            for (int j = 0; j < 4; ++j) {
                const int row = bm + wr * 64 + m * 16 + lr + j;
                const int col = bn + wc * 64 + n * 16 + lc;
                const float v = acc[m][n][j];
                OUT[(size_t)bz * NN * FF + (size_t)row * FF + col] =
                    v > 0.f ? v : __expf(v) - 1.f;
            }
        }
    }
}

extern "C" void kernel_launch(void* const* d_in, const int* in_sizes, int n_in,
                              void* d_out, int out_size, void* d_ws, size_t ws_size,
                              hipStream_t stream) {
    const float* h = (const float*)d_in[0];
    const float* W = (const float*)d_in[1];
    const float* a = (const float*)d_in[2];
    const float* A0 = (const float*)d_in[3];
    const float* A2 = (const float*)d_in[4];
    float* out = (float*)d_out;

    char* ws = (char*)d_ws;
    size_t ofs = 0;
    auto alloc = [&](size_t bytes) -> void* {
        void* p = ws + ofs;
        ofs = (ofs + bytes + 255) & ~(size_t)255;
        return p;
    };
    float* u12 = (float*)alloc(2 * FF * sizeof(float));
    float* Wh12 = (float*)alloc(2 * (size_t)BB * NN * sizeof(float));
    u16* WhThi = (u16*)alloc((size_t)BB * FF * NN * 2);
    u16* WhTlo = (u16*)alloc((size_t)BB * FF * NN * 2);
    u16* A0hi = (u16*)alloc((size_t)K4 * NN * 2);
    u16* A0lo = (u16*)alloc((size_t)K4 * NN * 2);
    u16* A2hi = (u16*)alloc((size_t)NN * K4 * 2);
    u16* A2lo = (u16*)alloc((size_t)NN * K4 * 2);

    // per-batch chunk bytes: S hi/lo + packed ADJ + Att hi/lo
    const size_t per_b =
        (size_t)NN * K4 * 2 * 2 + (size_t)NN * NN * 4 + (size_t)NN * NN * 2 * 2;
    int cb = BB;
    while (cb > 1 && ofs + (size_t)cb * per_b + 8192 > ws_size) cb >>= 1;
    u16* Shi = (u16*)alloc((size_t)cb * NN * K4 * 2);
    u16* Slo = (u16*)alloc((size_t)cb * NN * K4 * 2);
    u32* ADJ = (u32*)alloc((size_t)cb * NN * NN * 4);
    u16* AttHi = (u16*)alloc((size_t)cb * NN * NN * 2);
    u16* AttLo = (u16*)alloc((size_t)cb * NN * NN * 2);

    k_u<<<1, 128, 0, stream>>>(W, a, u12);
    k_wh12<<<BB * NN, 128, 0, stream>>>(h, u12, Wh12);
    k_whT<<<dim3((BB * NN) / 64, FF / 64), 256, 0, stream>>>(W, h, WhThi, WhTlo);
    k_split<<<(K4 * NN / 4 + 255) / 256, 256, 0, stream>>>(A0, A0hi, A0lo, K4 * NN / 4);
    k_split<<<(NN * K4 / 4 + 255) / 256, 256, 0, stream>>>(A2, A2hi, A2lo, NN * K4 / 4);

    for (int c0 = 0; c0 < BB; c0 += cb) {
        const int c = (BB - c0) < cb ? (BB - c0) : cb;
        const int mb1 = c * 2;   // M = c*512, BM = 256
        const int mb2 = c * 4;   // BM = 128
        // S = sigmoid(E @ A0^T), E on the fly
        k_g1<<<mb1 * (K4 / 256), 512, 0, stream>>>(Wh12, c0, A0hi, A0lo, Shi, Slo, mb1);
        // adj = S @ A2^T + e; mask -> packed ADJ
        k_g2<<<mb2 * (NN / 256), 512, 0, stream>>>(Shi, Slo, A2hi, A2lo, Wh12, c0, ADJ, mb2);
        k_softmax2<<<c * NN, 256, 0, stream>>>(ADJ, AttHi, AttLo);
        // out = elu(att @ Wh)
        k_pv<<<dim3(1, NN / 128, c), 256, 0, stream>>>(
            AttHi, AttLo, WhThi + (size_t)c0 * FF * NN, WhTlo + (size_t)c0 * FF * NN,
            out + (size_t)c0 * NN * FF);
    }
}

// Round 6
// 282.317 us; speedup vs baseline: 3.9753x; 1.0349x over previous
//
#include <hip/hip_runtime.h>

#define BB 32
#define NN 512
#define FF 128
#define K4 2048
#define ALPHA 0.2f
#define THRESH 0.6f
#define NEGINF -9e15f

typedef unsigned short u16;
typedef unsigned int u32;
typedef _Float16 f16;
typedef __attribute__((ext_vector_type(8))) _Float16 half8;
typedef __attribute__((ext_vector_type(4))) float f32x4;

union U16F { u16 u; f16 h; };
__device__ __forceinline__ u16 hbits(f16 h) { U16F x; x.h = h; return x.u; }
__device__ __forceinline__ float htof(u16 u) { U16F x; x.u = u; return (float)x.h; }
__device__ __forceinline__ void split2(float v, u16& hi, u16& lo) {
    f16 h = (f16)v;
    f16 l = (f16)(v - (float)h);
    hi = hbits(h);
    lo = hbits(l);
}
__device__ __forceinline__ float lrelu(float x) { return fmaxf(x, ALPHA * x); }

__device__ __forceinline__ void gload16(const void* g, void* l) {
    __builtin_amdgcn_global_load_lds(
        (__attribute__((address_space(1))) const unsigned int*)(unsigned long long)g,
        (__attribute__((address_space(3))) unsigned int*)(unsigned int)(unsigned long long)l,
        16, 0, 0);
}

// u1[f] = sum_g W[g,f]*a[g];  u2[f] = sum_g W[g,f]*a[F+g]
__global__ void k_u(const float* __restrict__ W, const float* __restrict__ a,
                    float* __restrict__ u12) {
    int f = threadIdx.x;
    float s1 = 0.f, s2 = 0.f;
    for (int g = 0; g < FF; ++g) {
        float w = W[g * FF + f];
        s1 += w * a[g];
        s2 += w * a[FF + g];
    }
    u12[f] = s1;
    u12[FF + f] = s2;
}

// Wh1[row] = h[row,:]·u1 ; Wh2[row] = h[row,:]·u2   (flat row = b*N+n)
__global__ void k_wh12(const float* __restrict__ h, const float* __restrict__ u12,
                       float* __restrict__ Wh12) {
    int row = blockIdx.x;
    int f = threadIdx.x;  // 128
    float hv = h[(size_t)row * FF + f];
    float p1 = hv * u12[f], p2 = hv * u12[FF + f];
#pragma unroll
    for (int o = 1; o < 64; o <<= 1) {
        p1 += __shfl_xor(p1, o, 64);
        p2 += __shfl_xor(p2, o, 64);
    }
    __shared__ float s1[2], s2[2];
    int w = f >> 6;
    if ((f & 63) == 0) { s1[w] = p1; s2[w] = p2; }
    __syncthreads();
    if (f == 0) {
        Wh12[row] = s1[0] + s1[1];
        Wh12[BB * NN + row] = s2[0] + s2[1];
    }
}

// WhT[b][f][n] = (h@W^T)[b][n][f] split into fp16 hi/lo (PV's B operand).
__global__ __launch_bounds__(256) void k_whT(const float* __restrict__ W,
                                             const float* __restrict__ h,
                                             u16* __restrict__ Thi, u16* __restrict__ Tlo) {
    const int bm = blockIdx.y * 64, bn = blockIdx.x * 64;
    __shared__ float As[32][68];
    __shared__ float Bs[32][68];
    int tid = threadIdx.x;
    int tx = tid & 15, ty = tid >> 4;
    float acc[4][4] = {{0.f}};
    int r = tid >> 3, q = tid & 7;
    const float* Ap = W + (size_t)(bm + r) * FF + q * 4;
    const float* Bp = h + (size_t)(bn + r) * FF + q * 4;
    for (int k0 = 0; k0 < FF; k0 += 32) {
        float4 a0 = *(const float4*)(Ap + k0);
        float4 a1 = *(const float4*)(Ap + k0 + 32 * FF);
        float4 b0 = *(const float4*)(Bp + k0);
        float4 b1 = *(const float4*)(Bp + k0 + 32 * FF);
        __syncthreads();
        As[q * 4 + 0][r] = a0.x; As[q * 4 + 1][r] = a0.y;
        As[q * 4 + 2][r] = a0.z; As[q * 4 + 3][r] = a0.w;
        As[q * 4 + 0][r + 32] = a1.x; As[q * 4 + 1][r + 32] = a1.y;
        As[q * 4 + 2][r + 32] = a1.z; As[q * 4 + 3][r + 32] = a1.w;
        Bs[q * 4 + 0][r] = b0.x; Bs[q * 4 + 1][r] = b0.y;
        Bs[q * 4 + 2][r] = b0.z; Bs[q * 4 + 3][r] = b0.w;
        Bs[q * 4 + 0][r + 32] = b1.x; Bs[q * 4 + 1][r + 32] = b1.y;
        Bs[q * 4 + 2][r + 32] = b1.z; Bs[q * 4 + 3][r + 32] = b1.w;
        __syncthreads();
#pragma unroll
        for (int kk = 0; kk < 32; ++kk) {
            float av[4], bv[4];
            *(float4*)av = *(const float4*)&As[kk][ty * 4];
            *(float4*)bv = *(const float4*)&Bs[kk][tx * 4];
#pragma unroll
            for (int i = 0; i < 4; ++i)
#pragma unroll
                for (int j = 0; j < 4; ++j) acc[i][j] = fmaf(av[i], bv[j], acc[i][j]);
        }
    }
#pragma unroll
    for (int i = 0; i < 4; ++i) {
        int f = bm + ty * 4 + i;
#pragma unroll
        for (int j = 0; j < 4; ++j) {
            int mg = bn + tx * 4 + j;
            u16 hi, lo;
            split2(acc[i][j], hi, lo);
            size_t idx = ((size_t)(mg >> 9) * FF + f) * NN + (mg & 511);
            Thi[idx] = hi;
            Tlo[idx] = lo;
        }
    }
}

// fp32 -> fp16 hi/lo split, vectorized
__global__ void k_split(const float* __restrict__ X, u16* __restrict__ Hi,
                        u16* __restrict__ Lo, int n4) {
    int i = blockIdx.x * 256 + threadIdx.x;
    if (i >= n4) return;
    float4 v = *(const float4*)(X + (size_t)i * 4);
    ushort4 hh, ll;
    split2(v.x, hh.x, ll.x);
    split2(v.y, hh.y, ll.y);
    split2(v.z, hh.z, ll.z);
    split2(v.w, hh.w, ll.w);
    *(ushort4*)(Hi + (size_t)i * 4) = hh;
    *(ushort4*)(Lo + (size_t)i * 4) = ll;
}

// GEMM1: S = sigmoid(E @ A0^T), E generated on the fly from Wh12.
// Tile 256x256, BK=32, 8 waves, 128KB LDS double-buffered.
// Wave-role stagger: parity p = w>>2 (one wave of each parity per SIMD).
// Per K-step: interval1 = {all: issue stage(t+1); p0: MFMA(t); p1: GEN(t+1)},
// barrier, interval2 = {p1: MFMA(t); p0: GEN(t+1)}, vmcnt(0)+lgkm(0), barrier.
// Each parity generates the A-half it consumes; B staging is split by parity.
__global__ __launch_bounds__(512, 2) void k_g1(const float* __restrict__ Wh12, int c0,
                                               const u16* __restrict__ Bhi,
                                               const u16* __restrict__ Blo,
                                               u16* __restrict__ Shi, u16* __restrict__ Slo,
                                               int mblocks) {
    __shared__ __align__(16) u16 lds[2][4][8192];
    __shared__ float wh1s[256];
    __shared__ float wh2s[512];
    const int tid = threadIdx.x;
    const int l = tid & 63, w = tid >> 6;
    const int p = w >> 2, wq = w & 3;
    const int nwg = gridDim.x, q = nwg >> 3;
    const int wg = (blockIdx.x & 7) * q + (blockIdx.x >> 3);
    const int nb = wg / mblocks, mb = wg % mblocks;
    const int bm = mb * 256, bn = nb * 256;
    const int bglob = c0 + (bm >> 9);

    if (tid < 256) wh1s[tid] = Wh12[(size_t)c0 * NN + bm + tid];
    wh2s[tid] = Wh12[BB * NN + (size_t)bglob * NN + tid];
    __syncthreads();

    f32x4 acc[8][4];
#pragma unroll
    for (int m = 0; m < 8; ++m)
#pragma unroll
        for (int n = 0; n < 4; ++n) acc[m][n] = (f32x4){0.f, 0.f, 0.f, 0.f};

    auto STAGE_MINE = [&](int buf, int k0) {
#pragma unroll
        for (int i = 0; i < 2; ++i) {
            const int g = p * 8 + wq * 2 + i;
            const size_t ro = (size_t)(bn + g * 16 + (l & 15)) * NN + k0 + ((l >> 4) * 8);
            gload16(Bhi + ro, &lds[buf][2][g * 512]);
            gload16(Blo + ro, &lds[buf][3][g * 512]);
        }
    };
    auto GEN_MINE = [&](int buf, int k0) {
        const int kc = k0 + (l >> 4) * 8;
        float w2v[8];
        *(float4*)&w2v[0] = *(const float4*)&wh2s[kc];
        *(float4*)&w2v[4] = *(const float4*)&wh2s[kc + 4];
#pragma unroll
        for (int i = 0; i < 2; ++i) {
            const int g = p * 8 + wq * 2 + i;
            const float w1 = wh1s[g * 16 + (l & 15)];
            u32 hh[4], llv[4];
#pragma unroll
            for (int jj = 0; jj < 4; ++jj) {
                float e0 = lrelu(w1 + w2v[2 * jj]);
                float e1 = lrelu(w1 + w2v[2 * jj + 1]);
                u16 h0, l0, h1, l1;
                split2(e0, h0, l0);
                split2(e1, h1, l1);
                hh[jj] = (u32)h0 | ((u32)h1 << 16);
                llv[jj] = (u32)l0 | ((u32)l1 << 16);
            }
            *(uint4*)&lds[buf][0][(g * 64 + l) * 8] = make_uint4(hh[0], hh[1], hh[2], hh[3]);
            *(uint4*)&lds[buf][1][(g * 64 + l) * 8] = make_uint4(llv[0], llv[1], llv[2], llv[3]);
        }
    };
    auto DO_MFMA = [&](int cur) {
        half8 bh[4], bl[4];
#pragma unroll
        for (int n = 0; n < 4; ++n) {
            const int gB = wq * 4 + n;
            bh[n] = *(const half8*)&lds[cur][2][(gB * 64 + l) * 8];
            bl[n] = *(const half8*)&lds[cur][3][(gB * 64 + l) * 8];
        }
        __builtin_amdgcn_s_setprio(1);
#pragma unroll
        for (int m = 0; m < 8; ++m) {
            const int gA = p * 8 + m;
            half8 ah = *(const half8*)&lds[cur][0][(gA * 64 + l) * 8];
            half8 al = *(const half8*)&lds[cur][1][(gA * 64 + l) * 8];
#pragma unroll
            for (int n = 0; n < 4; ++n)
                acc[m][n] = __builtin_amdgcn_mfma_f32_16x16x32_f16(ah, bh[n], acc[m][n], 0, 0, 0);
#pragma unroll
            for (int n = 0; n < 4; ++n)
                acc[m][n] = __builtin_amdgcn_mfma_f32_16x16x32_f16(al, bh[n], acc[m][n], 0, 0, 0);
#pragma unroll
            for (int n = 0; n < 4; ++n)
                acc[m][n] = __builtin_amdgcn_mfma_f32_16x16x32_f16(ah, bl[n], acc[m][n], 0, 0, 0);
        }
        __builtin_amdgcn_s_setprio(0);
    };

    // prologue: tile 0
    STAGE_MINE(0, 0);
    GEN_MINE(0, 0);
    asm volatile("s_waitcnt vmcnt(0) lgkmcnt(0)" ::: "memory");
    __syncthreads();

    for (int t = 0; t < 16; ++t) {
        const int cur = t & 1, k1 = (t + 1) * 32;
        const bool more = (t < 15);
        if (more) STAGE_MINE(cur ^ 1, k1);
        if (p == 0) DO_MFMA(cur);
        else if (more) GEN_MINE(cur ^ 1, k1);
        asm volatile("s_waitcnt lgkmcnt(0)" ::: "memory");
        __builtin_amdgcn_s_barrier();
        if (p == 1) DO_MFMA(cur);
        else if (more) GEN_MINE(cur ^ 1, k1);
        asm volatile("s_waitcnt vmcnt(0) lgkmcnt(0)" ::: "memory");
        __builtin_amdgcn_s_barrier();
    }

    const int lr = (l >> 4) * 4, lc = l & 15;
#pragma unroll
    for (int m = 0; m < 8; ++m) {
#pragma unroll
        for (int n = 0; n < 4; ++n) {
#pragma unroll
            for (int j = 0; j < 4; ++j) {
                const int row = bm + p * 128 + m * 16 + lr + j;
                const int col = bn + wq * 64 + n * 16 + lc;
                const float s = 1.f / (1.f + __expf(-acc[m][n][j]));
                u16 hi, lo;
                split2(s, hi, lo);
                const size_t idx = (size_t)row * K4 + col;
                Shi[idx] = hi;
                Slo[idx] = lo;
            }
        }
    }
}

// GEMM2: adj = S @ A2^T + e; mask -> packed ADJ (u32: lo<<16|hi of e, or ~0 if cut).
// Flattened M = c*512, N = 512, K = 2048. Tile 128x256, BK=32, 8 waves, 96 KB LDS.
__global__ __launch_bounds__(512, 2) void k_g2(const u16* __restrict__ Ahi,
                                               const u16* __restrict__ Alo,
                                               const u16* __restrict__ Bhi,
                                               const u16* __restrict__ Blo,
                                               const float* __restrict__ Wh12, int c0,
                                               u32* __restrict__ ADJ, int mblocks) {
    __shared__ __align__(16) u16 ldsA[2][2][4096];
    __shared__ __align__(16) u16 ldsB[2][2][8192];
    const int tid = threadIdx.x;
    const int l = tid & 63, w = tid >> 6;
    const int nwg = gridDim.x, q = nwg >> 3;
    const int wg = (blockIdx.x & 7) * q + (blockIdx.x >> 3);
    const int nb = wg / mblocks, mb = wg % mblocks;
    const int bm = mb * 128, bn = nb * 256;

    auto STAGE = [&](int buf, int k0) {
        const size_t ra = (size_t)(bm + w * 16 + (l & 15)) * K4 + k0 + ((l >> 4) * 8);
        gload16(Ahi + ra, &ldsA[buf][0][w * 512]);
        gload16(Alo + ra, &ldsA[buf][1][w * 512]);
#pragma unroll
        for (int i = 0; i < 2; ++i) {
            const int g = w * 2 + i;
            const size_t rb = (size_t)(bn + g * 16 + (l & 15)) * K4 + k0 + ((l >> 4) * 8);
            gload16(Bhi + rb, &ldsB[buf][0][g * 512]);
            gload16(Blo + rb, &ldsB[buf][1][g * 512]);
        }
    };

    f32x4 acc[4][4];
#pragma unroll
    for (int m = 0; m < 4; ++m)
#pragma unroll
        for (int n = 0; n < 4; ++n) acc[m][n] = (f32x4){0.f, 0.f, 0.f, 0.f};

    STAGE(0, 0);
    for (int t = 0; t < 64; ++t) {
        const int cur = t & 1;
        if (t < 63) {
            STAGE(cur ^ 1, (t + 1) * 32);
            asm volatile("s_waitcnt vmcnt(6)" ::: "memory");
        } else {
            asm volatile("s_waitcnt vmcnt(0)" ::: "memory");
        }
        __builtin_amdgcn_s_barrier();
        __builtin_amdgcn_sched_barrier(0);
        half8 bh[4], bl[4];
#pragma unroll
        for (int n = 0; n < 4; ++n) {
            const int gB = (w & 3) * 4 + n;
            bh[n] = *(const half8*)&ldsB[cur][0][(gB * 64 + l) * 8];
            bl[n] = *(const half8*)&ldsB[cur][1][(gB * 64 + l) * 8];
        }
        __builtin_amdgcn_s_setprio(1);
#pragma unroll
        for (int m = 0; m < 4; ++m) {
            const int gA = (w >> 2) * 4 + m;
            half8 ah = *(const half8*)&ldsA[cur][0][(gA * 64 + l) * 8];
            half8 al = *(const half8*)&ldsA[cur][1][(gA * 64 + l) * 8];
#pragma unroll
            for (int n = 0; n < 4; ++n)
                acc[m][n] = __builtin_amdgcn_mfma_f32_16x16x32_f16(ah, bh[n], acc[m][n], 0, 0, 0);
#pragma unroll
            for (int n = 0; n < 4; ++n)
                acc[m][n] = __builtin_amdgcn_mfma_f32_16x16x32_f16(al, bh[n], acc[m][n], 0, 0, 0);
#pragma unroll
            for (int n = 0; n < 4; ++n)
                acc[m][n] = __builtin_amdgcn_mfma_f32_16x16x32_f16(ah, bl[n], acc[m][n], 0, 0, 0);
        }
        __builtin_amdgcn_s_setprio(0);
        __builtin_amdgcn_sched_barrier(0);
        __builtin_amdgcn_s_barrier();
    }

    const int bglob = c0 + (bm >> 9);
    const float* wh2p = Wh12 + BB * NN + (size_t)bglob * NN;
    const int lr = (l >> 4) * 4, lc = l & 15;
#pragma unroll
    for (int m = 0; m < 4; ++m) {
#pragma unroll
        for (int n = 0; n < 4; ++n) {
#pragma unroll
            for (int j = 0; j < 4; ++j) {
                const int row = bm + (w >> 2) * 64 + m * 16 + lr + j;
                const int col = bn + (w & 3) * 64 + n * 16 + lc;
                const float e = lrelu(Wh12[(size_t)c0 * NN + row] + wh2p[col]);
                u32 pk = 0xFFFFFFFFu;
                if (e + acc[m][n][j] > THRESH) {
                    u16 hi, lo;
                    split2(e, hi, lo);
                    pk = (u32)hi | ((u32)lo << 16);
                }
                ADJ[(size_t)row * NN + col] = pk;
            }
        }
    }
}

// softmax rows of packed ADJ, write att as fp16 hi/lo
__global__ __launch_bounds__(256) void k_softmax2(const u32* __restrict__ ADJ,
                                                  u16* __restrict__ Hi, u16* __restrict__ Lo) {
    const size_t row = blockIdx.x;
    const u32* p = ADJ + row * NN;
    const int t = threadIdx.x;
    u32 w0 = p[t], w1 = p[t + 256];
    float v0 = (w0 == 0xFFFFFFFFu) ? NEGINF : htof((u16)(w0 & 0xFFFF)) + htof((u16)(w0 >> 16));
    float v1 = (w1 == 0xFFFFFFFFu) ? NEGINF : htof((u16)(w1 & 0xFFFF)) + htof((u16)(w1 >> 16));
    float m = fmaxf(v0, v1);
#pragma unroll
    for (int o = 1; o < 64; o <<= 1) m = fmaxf(m, __shfl_xor(m, o, 64));
    __shared__ float red[4], red2[4];
    int w = t >> 6;
    if ((t & 63) == 0) red[w] = m;
    __syncthreads();
    m = fmaxf(fmaxf(red[0], red[1]), fmaxf(red[2], red[3]));
    float e0 = __expf(v0 - m), e1 = __expf(v1 - m);
    float s = e0 + e1;
#pragma unroll
    for (int o = 1; o < 64; o <<= 1) s += __shfl_xor(s, o, 64);
    if ((t & 63) == 0) red2[w] = s;
    __syncthreads();
    s = red2[0] + red2[1] + red2[2] + red2[3];
    float inv = 1.f / s;
    float a0 = e0 * inv, a1 = e1 * inv;
    u16 h0, l0, h1, l1;
    split2(a0, h0, l0);
    split2(a1, h1, l1);
    Hi[row * NN + t] = h0;
    Hi[row * NN + t + 256] = h1;
    Lo[row * NN + t] = l0;
    Lo[row * NN + t + 256] = l1;
}

// PV: out = elu(att @ Wh), 128x128 tile, depth-2 pipeline.
__global__ __launch_bounds__(256) void k_pv(const u16* __restrict__ Ahi,
                                            const u16* __restrict__ Alo,
                                            const u16* __restrict__ Bhi,
                                            const u16* __restrict__ Blo,
                                            float* __restrict__ OUT) {
    __shared__ __align__(16) u16 lds[2][4][4096];
    const int tid = threadIdx.x;
    const int l = tid & 63, w = tid >> 6;
    const int wr = w >> 1, wc = w & 1;
    const int bz = blockIdx.z;
    const int bm = blockIdx.y * 128, bn = 0;

    const u16* A0p = Ahi + (size_t)bz * NN * NN;
    const u16* A1p = Alo + (size_t)bz * NN * NN;
    const u16* B0p = Bhi + (size_t)bz * FF * NN;
    const u16* B1p = Blo + (size_t)bz * FF * NN;

    const int g0 = w, g1 = w + 4;
    const size_t offA0 = (size_t)(bm + g0 * 16 + (l & 15)) * NN + (l >> 4) * 8;
    const size_t offA1 = (size_t)(bm + g1 * 16 + (l & 15)) * NN + (l >> 4) * 8;
    const size_t offB0 = (size_t)(bn + g0 * 16 + (l & 15)) * NN + (l >> 4) * 8;
    const size_t offB1 = (size_t)(bn + g1 * 16 + (l & 15)) * NN + (l >> 4) * 8;

    auto STAGE = [&](int buf, int kk) {
        gload16(A0p + offA0 + kk, &lds[buf][0][g0 * 512]);
        gload16(A0p + offA1 + kk, &lds[buf][0][g1 * 512]);
        gload16(A1p + offA0 + kk, &lds[buf][1][g0 * 512]);
        gload16(A1p + offA1 + kk, &lds[buf][1][g1 * 512]);
        gload16(B0p + offB0 + kk, &lds[buf][2][g0 * 512]);
        gload16(B0p + offB1 + kk, &lds[buf][2][g1 * 512]);
        gload16(B1p + offB0 + kk, &lds[buf][3][g0 * 512]);
        gload16(B1p + offB1 + kk, &lds[buf][3][g1 * 512]);
    };

    f32x4 acc[4][4];
#pragma unroll
    for (int m = 0; m < 4; ++m)
#pragma unroll
        for (int n = 0; n < 4; ++n) acc[m][n] = (f32x4){0.f, 0.f, 0.f, 0.f};

    STAGE(0, 0);
    for (int t = 0; t < 16; ++t) {
        const int cur = t & 1;
        if (t + 1 < 16) {
            STAGE(cur ^ 1, (t + 1) * 32);
            asm volatile("s_waitcnt vmcnt(8)" ::: "memory");
        } else {
            asm volatile("s_waitcnt vmcnt(0)" ::: "memory");
        }
        __builtin_amdgcn_s_barrier();
        __builtin_amdgcn_sched_barrier(0);
        half8 ah[4], al[4], bh[4], bl[4];
#pragma unroll
        for (int m = 0; m < 4; ++m) {
            ah[m] = *(const half8*)&lds[cur][0][((wr * 4 + m) * 64 + l) * 8];
            al[m] = *(const half8*)&lds[cur][1][((wr * 4 + m) * 64 + l) * 8];
        }
#pragma unroll
        for (int n = 0; n < 4; ++n) {
            bh[n] = *(const half8*)&lds[cur][2][((wc * 4 + n) * 64 + l) * 8];
            bl[n] = *(const half8*)&lds[cur][3][((wc * 4 + n) * 64 + l) * 8];
        }
#pragma unroll
        for (int m = 0; m < 4; ++m) {
#pragma unroll
            for (int n = 0; n < 4; ++n)
                acc[m][n] = __builtin_amdgcn_mfma_f32_16x16x32_f16(ah[m], bh[n], acc[m][n], 0, 0, 0);
        }
#pragma unroll
        for (int m = 0; m < 4; ++m) {
#pragma unroll
            for (int n = 0; n < 4; ++n) {
                acc[m][n] = __builtin_amdgcn_mfma_f32_16x16x32_f16(al[m], bh[n], acc[m][n], 0, 0, 0);
                acc[m][n] = __builtin_amdgcn_mfma_f32_16x16x32_f16(ah[m], bl[n], acc[m][n], 0, 0, 0);
            }
        }
        __builtin_amdgcn_s_barrier();
    }

    const int lr = (l >> 4) * 4, lc = l & 15;
#pragma unroll
    for (int m = 0; m < 4; ++m) {
#pragma unroll
        for (int n = 0; n < 4; ++n) {
#pragma unroll
            for (int j = 0; j < 4; ++j) {
                const int row = bm + wr * 64 + m * 16 + lr + j;
                const int col = bn + wc * 64 + n * 16 + lc;
                const float v = acc[m][n][j];
                OUT[(size_t)bz * NN * FF + (size_t)row * FF + col] =
                    v > 0.f ? v : __expf(v) - 1.f;
            }
        }
    }
}

extern "C" void kernel_launch(void* const* d_in, const int* in_sizes, int n_in,
                              void* d_out, int out_size, void* d_ws, size_t ws_size,
                              hipStream_t stream) {
    const float* h = (const float*)d_in[0];
    const float* W = (const float*)d_in[1];
    const float* a = (const float*)d_in[2];
    const float* A0 = (const float*)d_in[3];
    const float* A2 = (const float*)d_in[4];
    float* out = (float*)d_out;

    char* ws = (char*)d_ws;
    size_t ofs = 0;
    auto alloc = [&](size_t bytes) -> void* {
        void* p = ws + ofs;
        ofs = (ofs + bytes + 255) & ~(size_t)255;
        return p;
    };
    float* u12 = (float*)alloc(2 * FF * sizeof(float));
    float* Wh12 = (float*)alloc(2 * (size_t)BB * NN * sizeof(float));
    u16* WhThi = (u16*)alloc((size_t)BB * FF * NN * 2);
    u16* WhTlo = (u16*)alloc((size_t)BB * FF * NN * 2);
    u16* A0hi = (u16*)alloc((size_t)K4 * NN * 2);
    u16* A0lo = (u16*)alloc((size_t)K4 * NN * 2);
    u16* A2hi = (u16*)alloc((size_t)NN * K4 * 2);
    u16* A2lo = (u16*)alloc((size_t)NN * K4 * 2);

    // per-batch chunk bytes: S hi/lo + packed ADJ + Att hi/lo
    const size_t per_b =
        (size_t)NN * K4 * 2 * 2 + (size_t)NN * NN * 4 + (size_t)NN * NN * 2 * 2;
    int cb = BB;
    while (cb > 1 && ofs + (size_t)cb * per_b + 8192 > ws_size) cb >>= 1;
    u16* Shi = (u16*)alloc((size_t)cb * NN * K4 * 2);
    u16* Slo = (u16*)alloc((size_t)cb * NN * K4 * 2);
    u32* ADJ = (u32*)alloc((size_t)cb * NN * NN * 4);
    u16* AttHi = (u16*)alloc((size_t)cb * NN * NN * 2);
    u16* AttLo = (u16*)alloc((size_t)cb * NN * NN * 2);

    k_u<<<1, 128, 0, stream>>>(W, a, u12);
    k_wh12<<<BB * NN, 128, 0, stream>>>(h, u12, Wh12);
    k_whT<<<dim3((BB * NN) / 64, FF / 64), 256, 0, stream>>>(W, h, WhThi, WhTlo);
    k_split<<<(K4 * NN / 4 + 255) / 256, 256, 0, stream>>>(A0, A0hi, A0lo, K4 * NN / 4);
    k_split<<<(NN * K4 / 4 + 255) / 256, 256, 0, stream>>>(A2, A2hi, A2lo, NN * K4 / 4);

    for (int c0 = 0; c0 < BB; c0 += cb) {
        const int c = (BB - c0) < cb ? (BB - c0) : cb;
        const int mb1 = c * 2;   // M = c*512, BM = 256
        const int mb2 = c * 4;   // BM = 128
        // S = sigmoid(E @ A0^T), E on the fly, staggered wave roles
        k_g1<<<mb1 * (K4 / 256), 512, 0, stream>>>(Wh12, c0, A0hi, A0lo, Shi, Slo, mb1);
        // adj = S @ A2^T + e; mask -> packed ADJ
        k_g2<<<mb2 * (NN / 256), 512, 0, stream>>>(Shi, Slo, A2hi, A2lo, Wh12, c0, ADJ, mb2);
        k_softmax2<<<c * NN, 256, 0, stream>>>(ADJ, AttHi, AttLo);
        // out = elu(att @ Wh)
        k_pv<<<dim3(1, NN / 128, c), 256, 0, stream>>>(
            AttHi, AttLo, WhThi + (size_t)c0 * FF * NN, WhTlo + (size_t)c0 * FF * NN,
            out + (size_t)c0 * NN * FF);
    }
}